// Round 9
// baseline (162.203 us; speedup 1.0000x reference)
//
#include <hip/hip_runtime.h>
#include <hip/hip_bf16.h>

// Ensemble Q-network, fused, transposed ([features x batch]).
//   h1^T = relu(W1^T x^T + b1);  acc = W2^T h1^T + b2;  out = W3 . relu(acc)  in-register.
// R9: PERSISTENT blocks with W2 REGISTER-RESIDENT. 520 blocks (52 per net) x 256 thr
// (4 waves), BT=64, 2 blocks/CU at <=256 VGPR (launch_bounds(256,2)). Each wave holds
// its 64-channel W2 slice as 32 resident b128 frags (128 VGPRs), loaded ONCE per
// block; the layer-2 K-loop then reads ONLY LDS (h1 B-frags, even/odd slot rotation)
// -> no L2-latency dependency in the hot loop. Blocks iterate over ~10 batch tiles.

typedef __attribute__((ext_vector_type(8))) short bf16x8;   // 8 bf16 (4 VGPRs)
typedef __attribute__((ext_vector_type(4))) float f32x4;    // MFMA C/D

#define B_TOTAL 32768
#define NQ 10
#define HDIM 256
#define BT 64               // batch cols per tile
#define TILES 512           // tiles per net
#define BPN 52              // blocks per net (grid = 10*52 = 520)

#define XP_ELEMS  (B_TOTAL * 32)            // bf16 x, k-padded to 32
#define W1P_ELEMS (NQ * 16 * 64 * 8)        // [n][mtile16][lane64][j8]
#define W2P_ELEMS (NQ * 8 * 16 * 64 * 8)    // [n][kt8][mtile16][lane64][j8]

__device__ __forceinline__ unsigned short f2bf(float f) {
  unsigned int u = __float_as_uint(f);
  u = u + 0x7FFFu + ((u >> 16) & 1u);
  return (unsigned short)(u >> 16);
}

__device__ __forceinline__ unsigned int pk2bf(float a, float b) {
  union { __hip_bfloat162 h; unsigned int u; } cv;
  cv.h = __float22bfloat162_rn(make_float2(a, b));
  return cv.u;
}

// ---- single pack dispatch: x, W1^T (16x16 A-order), W2^T (16x16 A-order) ----
__global__ void pack_all_kernel(const float* __restrict__ state,
                                const float* __restrict__ action,
                                const float* __restrict__ W1,
                                const float* __restrict__ W2,
                                unsigned short* __restrict__ xp,
                                unsigned short* __restrict__ w1p,
                                unsigned short* __restrict__ w2p) {
  int t = blockIdx.x * 256 + threadIdx.x;   // 872 * 256 = 223232 exactly
  const int NX  = B_TOTAL * 4;              // 131072 uint4 chunks of xp
  const int NW1 = NQ * 16 * 64;             // 10240
  if (t < NX) {
    int b = t >> 2, seg = t & 3;
    unsigned short v[8];
    if (seg < 2) {
      const float* sp = state + (size_t)b * 17 + seg * 8;
#pragma unroll
      for (int j = 0; j < 8; j++) v[j] = f2bf(sp[j]);
    } else if (seg == 2) {
      v[0] = f2bf(state[(size_t)b * 17 + 16]);
#pragma unroll
      for (int j = 0; j < 6; j++) v[1 + j] = f2bf(action[(size_t)b * 6 + j]);
      v[7] = 0;
    } else {
#pragma unroll
      for (int j = 0; j < 8; j++) v[j] = 0;
    }
    *(uint4*)&xp[(size_t)t * 8] = *(const uint4*)v;
  } else if (t < NX + NW1) {
    int u = t - NX;
    int lane = u & 63, mt = (u >> 6) & 15, n = u >> 10;
    int m = lane & 15, q = lane >> 4;
    int outc = mt * 16 + m;
    unsigned short v[8];
#pragma unroll
    for (int j = 0; j < 8; j++) {
      int k = q * 8 + j;
      v[j] = (k < 23) ? f2bf(W1[(n * 23 + k) * 256 + outc]) : (unsigned short)0;
    }
    *(uint4*)&w1p[(size_t)u * 8] = *(const uint4*)v;
  } else {
    int u = t - NX - NW1;                   // < 81920
    int lane = u & 63, mt = (u >> 6) & 15, kt = (u >> 10) & 7, n = u >> 13;
    int m = lane & 15, q = lane >> 4;
    int outc = mt * 16 + m;
    unsigned short v[8];
#pragma unroll
    for (int j = 0; j < 8; j++) {
      int h = kt * 32 + q * 8 + j;
      v[j] = f2bf(W2[((size_t)(n * 256 + h)) * 256 + outc]);
    }
    *(uint4*)&w2p[(size_t)u * 8] = *(const uint4*)v;
  }
}

// ---- fused MLP: 520 persistent blocks x 256 threads (4 waves), 2 blocks/CU ----
// wave w (=0..3) owns channels [w*64, w*64+64) and ALL 64 batch cols of the tile.
__global__ __launch_bounds__(256, 2) void fused_ensemble_kernel(
    const unsigned short* __restrict__ xp,
    const unsigned short* __restrict__ w1p,
    const float* __restrict__ b1,
    const unsigned short* __restrict__ w2p,
    const float* __restrict__ b2,
    const float* __restrict__ W3,
    const float* __restrict__ b3,
    float* __restrict__ out) {
  __shared__ __align__(16) unsigned short hs[32 * BT * 8];  // 32 KB, [ch/8][col][8]
  __shared__ float red[4 * BT];                             // 1 KB cross-wave reduce

  const int tid = threadIdx.x;
  const int lane = tid & 63;
  const int w = tid >> 6;       // wave = channel group (64 ch)
  const int m = lane & 15;
  const int q = lane >> 4;

  const int n = blockIdx.x / BPN;
  const int slot = blockIdx.x - n * BPN;

  const unsigned short* w2n = w2p + (size_t)n * (8 * 16 * 64 * 8);

  // ---- W2 slice -> registers, ONCE per block: 32 b128 frags = 128 VGPRs ----
  bf16x8 aW[8][4];
#pragma unroll
  for (int kt = 0; kt < 8; kt++)
#pragma unroll
    for (int mt = 0; mt < 4; mt++)
      aW[kt][mt] = *(const bf16x8*)(w2n + (((size_t)kt * 16 + w * 4 + mt) * 64 + lane) * 8);

  const float b3n = b3[n];

  for (int tile = slot; tile < TILES; tile += BPN) {
    const int row0 = tile * BT;

    // ---- layer 1: 16x16x32, single K-step; wave tile 64ch x 64col (4x4 frags) ----
    f32x4 acc[4][4];
    {
      bf16x8 af[4], bfr[4];
#pragma unroll
      for (int nt = 0; nt < 4; nt++) {
        int col = row0 + nt * 16 + m;
        bfr[nt] = *(const bf16x8*)(xp + (size_t)col * 32 + q * 8);
      }
#pragma unroll
      for (int mt = 0; mt < 4; mt++)
        af[mt] = *(const bf16x8*)(w1p + (((size_t)n * 16 + w * 4 + mt) * 64 + lane) * 8);
#pragma unroll
      for (int mt = 0; mt < 4; mt++) {
        float4 bv = *(const float4*)&b1[n * HDIM + (w * 4 + mt) * 16 + q * 4];
        f32x4 bi = (f32x4){bv.x, bv.y, bv.z, bv.w};
#pragma unroll
        for (int nt = 0; nt < 4; nt++) acc[mt][nt] = bi;
      }
#pragma unroll
      for (int nt = 0; nt < 4; nt++)
#pragma unroll
        for (int mt = 0; mt < 4; mt++)
          acc[mt][nt] = __builtin_amdgcn_mfma_f32_16x16x32_bf16(af[mt], bfr[nt], acc[mt][nt], 0, 0, 0);
    }

    // ---- epilogue 1: relu -> h1 bf16, frag-chunk layout [ch/8][col][8] ----
#pragma unroll
    for (int mt = 0; mt < 4; mt++) {
      int kq = w * 8 + mt * 2 + (q >> 1);
      int joff = (q & 1) * 4;
#pragma unroll
      for (int nt = 0; nt < 4; nt++) {
        int col = nt * 16 + m;
        f32x4 a = acc[mt][nt];
        uint2 wv;
        wv.x = pk2bf(fmaxf(a[0], 0.f), fmaxf(a[1], 0.f));
        wv.y = pk2bf(fmaxf(a[2], 0.f), fmaxf(a[3], 0.f));
        *(uint2*)&hs[((size_t)kq * BT + col) * 8 + joff] = wv;
      }
    }

    // layer-2 bias init (L2-hot loads, overlap with barrier)
    f32x4 acc2[4][4];
#pragma unroll
    for (int mt = 0; mt < 4; mt++) {
      float4 bv = *(const float4*)&b2[n * HDIM + (w * 4 + mt) * 16 + q * 4];
      f32x4 bi = (f32x4){bv.x, bv.y, bv.z, bv.w};
#pragma unroll
      for (int nt = 0; nt < 4; nt++) acc2[mt][nt] = bi;
    }
    __syncthreads();

    // ---- layer 2: 8 K-steps, LDS-only B-frags, even/odd slot rotation ----
    {
      bf16x8 bS[2][4];
#pragma unroll
      for (int sl = 0; sl < 2; sl++)
#pragma unroll
        for (int nt = 0; nt < 4; nt++)
          bS[sl][nt] = *(const bf16x8*)&hs[(((size_t)sl * 4 + q) * BT + nt * 16 + m) * 8];

#pragma unroll
      for (int kt = 0; kt < 8; kt++) {
        const int sl = kt & 1;
#pragma unroll
        for (int nt = 0; nt < 4; nt++)
#pragma unroll
          for (int mt = 0; mt < 4; mt++)
            acc2[mt][nt] = __builtin_amdgcn_mfma_f32_16x16x32_bf16(
                aW[kt][mt], bS[sl][nt], acc2[mt][nt], 0, 0, 0);
        if (kt + 2 < 8) {
#pragma unroll
          for (int nt = 0; nt < 4; nt++)
            bS[sl][nt] = *(const bf16x8*)&hs[(((size_t)(kt + 2) * 4 + q) * BT + nt * 16 + m) * 8];
        }
      }
    }

    // ---- layer 3 in-register: p[col] = sum_ch relu(acc2_ch) * W3[ch]; reduce ----
    {
      float4 w3v[4];
#pragma unroll
      for (int mt = 0; mt < 4; mt++)
        w3v[mt] = *(const float4*)&W3[n * HDIM + (w * 4 + mt) * 16 + q * 4];
      float p[4];
#pragma unroll
      for (int nt = 0; nt < 4; nt++) {
        float s = 0.f;
#pragma unroll
        for (int mt = 0; mt < 4; mt++) {
          f32x4 a = acc2[mt][nt];
          float4 wv = w3v[mt];
          s = fmaf(fmaxf(a[0], 0.f), wv.x, s);
          s = fmaf(fmaxf(a[1], 0.f), wv.y, s);
          s = fmaf(fmaxf(a[2], 0.f), wv.z, s);
          s = fmaf(fmaxf(a[3], 0.f), wv.w, s);
        }
        s += __shfl_xor(s, 16, 64);   // reduce q within wave (channels)
        s += __shfl_xor(s, 32, 64);
        p[nt] = s;
      }
      if (q == 0) {
#pragma unroll
        for (int nt = 0; nt < 4; nt++) red[w * BT + nt * 16 + m] = p[nt];
      }
      __syncthreads();   // also guards hs reuse by next tile's epilogue
      if (tid < BT) {
        float s = b3n;
#pragma unroll
        for (int c = 0; c < 4; c++) s += red[c * BT + tid];
        out[(size_t)n * B_TOTAL + row0 + tid] = s;
      }
    }
  }
}

extern "C" void kernel_launch(void* const* d_in, const int* in_sizes, int n_in,
                              void* d_out, int out_size, void* d_ws, size_t ws_size,
                              hipStream_t stream) {
  const float* state  = (const float*)d_in[0];
  const float* action = (const float*)d_in[1];
  const float* W1 = (const float*)d_in[2];
  const float* b1 = (const float*)d_in[3];
  const float* W2 = (const float*)d_in[4];
  const float* b2 = (const float*)d_in[5];
  const float* W3 = (const float*)d_in[6];
  const float* b3 = (const float*)d_in[7];
  float* out = (float*)d_out;

  unsigned short* xp  = (unsigned short*)d_ws;                                    // 2,097,152 B
  unsigned short* w1p = (unsigned short*)((char*)d_ws + (size_t)XP_ELEMS * 2);    //   163,840 B
  unsigned short* w2p = (unsigned short*)((char*)d_ws + (size_t)(XP_ELEMS + W1P_ELEMS) * 2); // 1,310,720 B

  pack_all_kernel<<<872, 256, 0, stream>>>(state, action, W1, W2, xp, w1p, w2p);
  fused_ensemble_kernel<<<NQ * BPN, 256, 0, stream>>>(
      xp, w1p, b1, w2p, b2, W3, b3, out);
}